// Round 18
// baseline (158.592 us; speedup 1.0000x reference)
//
#include <hip/hip_runtime.h>

typedef __attribute__((ext_vector_type(2)))  float  f32x2;
typedef __attribute__((ext_vector_type(4)))  float  f32x4;
typedef __attribute__((ext_vector_type(16))) float  f32x16;
typedef __attribute__((ext_vector_type(8)))  short  short8;
typedef __attribute__((ext_vector_type(4)))  unsigned int u32x4;
typedef __attribute__((ext_vector_type(2)))  unsigned int uint2v;

#define MFMA16 __builtin_amdgcn_mfma_f32_16x16x32_bf16
#define MFMA32 __builtin_amdgcn_mfma_f32_32x32x16_bf16

static __device__ __forceinline__ unsigned short f2bf(float f){
  union { float f; unsigned u; } v; v.f = f;
  unsigned r = v.u + 0x7fffu + ((v.u >> 16) & 1u);
  return (unsigned short)(r >> 16);
}

static __device__ __forceinline__ unsigned cvtpk(float a, float b){
  unsigned r;
  asm("v_cvt_pk_bf16_f32 %0, %1, %2" : "=v"(r) : "v"(a), "v"(b));
  return r;
}

// v_permlane32_swap_b32: a' = {a.lo, b.lo-values}, b' = {a.hi-values, b.hi}
static __device__ __forceinline__ void plswap(unsigned &a, unsigned &b){
  asm("v_permlane32_swap_b32 %0, %1" : "+v"(a), "+v"(b));
}

typedef __attribute__((address_space(1))) void gvoid_t;
typedef __attribute__((address_space(3))) void lvoid_t;

static __device__ __forceinline__ void gll16(const unsigned short* g, unsigned short* l){
  __builtin_amdgcn_global_load_lds((gvoid_t*)g, (lvoid_t*)l, 16, 0, 0);
}

// MFMA-image layout for a [M][1024] bf16 matrix (GEMM staging):
//   chunk = (mblk*16 + kt)*2 + kh ; elem = chunk*8192 + band*512 + c*128 + ri*8 + ke
// Attention fragment images (per bh, per 64-key tile of 4096 elems):
//   Q/K: elem = (row>>5)*2048 + ds*512 + (((d>>3)&1)*32 + (row&31))*8 + (d&7), ds=d>>4
//   V:   elem = (key>>6)*4096 + (((key>>4)&3)*2 + (d>>5))*512 + (((key>>3)&1)*32 + (d&31))*8 + (key&7)

// ---------------- prep: x convert (blocks 0..511) + both W transposes ----------------
__global__ __launch_bounds__(256) void k_prep(const float* __restrict__ x,
                                              unsigned short* __restrict__ xb,
                                              const float* __restrict__ Wq,
                                              unsigned short* __restrict__ Wqt,
                                              const float* __restrict__ Wp,
                                              unsigned short* __restrict__ Wpt){
  __shared__ __align__(16) unsigned char smraw[32768];
  const int bid = blockIdx.x, t = threadIdx.x;
  if (bid < 512){
    unsigned short* sm = (unsigned short*)smraw;     // 256 rows x 64 k
    const int mblk = bid >> 4, kt = bid & 15;
    const int l16 = t & 15, rg = t >> 4;
    #pragma unroll
    for (int p = 0; p < 16; p++){
      int row = p * 16 + rg;
      f32x4 v = *(const f32x4*)&x[(size_t)(mblk*256 + row) * 1024 + kt*64 + l16*4];
      uint2v u; u[0] = cvtpk(v[0], v[1]); u[1] = cvtpk(v[2], v[3]);
      int g = l16 >> 1;
      *(uint2v*)&sm[row*64 + ((g ^ (row & 7)) << 3) + (l16 & 1)*4] = u;
    }
    __syncthreads();
    size_t obase = (size_t)((mblk*16 + kt)*2) * 8192;
    #pragma unroll
    for (int i = 0; i < 8; i++){
      int o = i * 256 + t;
      int kh = o >> 10, rem = o & 1023;
      int band = rem >> 6, cc = (rem >> 4) & 3, ri = rem & 15;
      int r = band*16 + ri, g = kh*4 + cc;
      short8 vv = *(const short8*)&sm[r*64 + ((g ^ (r & 7)) << 3)];
      *(short8*)&xb[obase + (size_t)kh*8192 + rem*8] = vv;
    }
  } else {
    float (*tile)[33] = (float(*)[33])smraw;         // 32 x 33 floats
    int wid = bid - 512;
    const float* W; unsigned short* Wt; int N, n0, k0;
    if (wid < 3072){ W = Wq; Wt = Wqt; N = 3072; n0 = (wid % 96)*32; k0 = (wid / 96)*32; }
    else { wid -= 3072; W = Wp; Wt = Wpt; N = 1024; n0 = (wid & 31)*32; k0 = (wid >> 5)*32; }
    const int tx = t & 31, ty = t >> 5;   // 32 x 8
    #pragma unroll
    for (int r = 0; r < 4; r++)
      tile[ty + 8*r][tx] = W[(size_t)(k0 + ty + 8*r) * N + n0 + tx];
    __syncthreads();
    #pragma unroll
    for (int r = 0; r < 4; r++){
      int nn = ty + 8*r;
      int n = n0 + nn, k = k0 + tx;
      int kt = k >> 6, kh = (k >> 5) & 1, cc = (k >> 3) & 3, ke = k & 7;
      int nblk = n >> 8, band = (n & 255) >> 4, ri = n & 15;
      Wt[(size_t)(((nblk*16 + kt)*2 + kh)) * 8192 + band*512 + cc*128 + ri*8 + ke] =
          f2bf(tile[tx][nn]);
    }
  }
}

// end-of-phase sync with counted vmcnt (N = literal token)
#define VMW(N) { __builtin_amdgcn_sched_barrier(0);                        \
                 asm volatile("s_waitcnt vmcnt(" #N ")" ::: "memory");     \
                 __builtin_amdgcn_s_barrier();                             \
                 __builtin_amdgcn_sched_barrier(0); }

// ---------------- QKV GEMM, 128x256 tile, 8 waves, 3-buffer slice pipeline ----
__global__ __launch_bounds__(512, 4) void k_gemm0(const unsigned short* __restrict__ A,
                                                  const unsigned short* __restrict__ Bt,
                                                  const float* __restrict__ bias,
                                                  unsigned short* __restrict__ qg,
                                                  int NT){
  __shared__ __align__(16) unsigned short lds[36864];
  const int t = threadIdx.x, w = t >> 6, l = t & 63;
  const int wr = w >> 2, wc = w & 3;
  const int bx = blockIdx.x, by = blockIdx.y;
  const int mblk = bx >> 1, mhalf = bx & 1;

  const unsigned short* Ab = A + (size_t)mblk*262144 + mhalf*4096 + t*8;
  const unsigned short* Bb = Bt + (size_t)by*262144 + t*8;

  f32x4 acc[4][4];
  #pragma unroll
  for (int i = 0; i < 4; i++)
    #pragma unroll
    for (int j = 0; j < 4; j++)
      acc[i][j] = (f32x4){0.f, 0.f, 0.f, 0.f};

  auto stage = [&](int sl){
    const int b = sl % 3;
    const size_t off = (size_t)sl * 8192;
    gll16(Ab + off,        &lds[b*12288 + t*8]);
    gll16(Bb + off,        &lds[b*12288 + 4096 + t*8]);
    gll16(Bb + off + 4096, &lds[b*12288 + 8192 + t*8]);
  };

  auto phase = [&](int b, bool do_stage, int sl){
    short8 af[4], bfr[4];
    const int aoff = b*12288 + wr*2048 + l*8;
    const int boff = b*12288 + 4096 + wc*2048 + l*8;
    #pragma unroll
    for (int i = 0; i < 4; i++) af[i]  = *(const short8*)&lds[aoff + i*512];
    #pragma unroll
    for (int j = 0; j < 4; j++) bfr[j] = *(const short8*)&lds[boff + j*512];
    if (do_stage) stage(sl);
    __builtin_amdgcn_sched_barrier(0);
    __builtin_amdgcn_s_barrier();
    __builtin_amdgcn_s_setprio(1);
    #pragma unroll
    for (int i = 0; i < 4; i++)
      #pragma unroll
      for (int j = 0; j < 4; j++)
        acc[i][j] = MFMA16(af[i], bfr[j], acc[i][j], 0, 0, 0);
    __builtin_amdgcn_s_setprio(0);
  };

  stage(0); stage(1);
  VMW(3);

  const int NP = 2 * NT;
  int p = 0;
  for (; p <= NP - 3; ++p){
    phase(p % 3, true, p + 2);
    VMW(3);
  }
  phase(p % 3, false, 0); VMW(0); ++p;
  phase(p % 3, false, 0);

  unsigned short* kg = qg + (size_t)8388608;
  unsigned short* vg = kg + (size_t)8388608;
  const int which = by >> 2;   // 0=q, 1=k, 2=v (block-uniform)
  const int lrow = l & 15;
  #pragma unroll
  for (int j = 0; j < 4; j++){
    int col = by*256 + wc*64 + j*16 + lrow;
    float bi = bias[col];
    int cc = col & 1023;
    int h = cc >> 6;
    int d = j*16 + lrow;
    if (which == 2){
      int db = d >> 5, dd = d & 31;
      #pragma unroll
      for (int i = 0; i < 4; i++){
        int nn = bx*128 + wr*64 + i*16 + (l >> 4)*4;
        int b = nn >> 11, key = nn & 2047;
        size_t idx = (size_t)(key >> 6)*4096 + (size_t)(((key >> 4) & 3)*2 + db)*512
                   + (((key >> 3) & 1)*32 + dd)*8 + (key & 7);
        uint2v u;
        u[0] = cvtpk(acc[i][j][0] + bi, acc[i][j][1] + bi);
        u[1] = cvtpk(acc[i][j][2] + bi, acc[i][j][3] + bi);
        *(uint2v*)&vg[(size_t)(b*16 + h)*131072 + idx] = u;
      }
    } else {
      unsigned short* dst = which ? kg : qg;
      float scale = which ? 1.0f : 0.18033688011f;  // 0.125 * log2(e) for q
      int dsub = (d >> 4)*512 + ((d >> 3) & 1)*256 + (d & 7);
      #pragma unroll
      for (int i = 0; i < 4; i++)
        #pragma unroll
        for (int reg = 0; reg < 4; reg++){
          int nn = bx*128 + wr*64 + i*16 + (l >> 4)*4 + reg;
          int b = nn >> 11, row = nn & 2047;
          dst[(size_t)(b*16 + h)*131072 + (size_t)(row >> 5)*2048 + dsub + (row & 31)*8] =
              f2bf((acc[i][j][reg] + bi) * scale);
        }
    }
  }
}

// ---------------- proj GEMM, 128x128 tile, grid (64,8)=512 blocks, 24KB LDS ----
__global__ __launch_bounds__(512, 4) void k_gemmP(const unsigned short* __restrict__ A,
                                                  const unsigned short* __restrict__ Bt,
                                                  const float* __restrict__ bias,
                                                  float* __restrict__ out,
                                                  int NT){
  __shared__ __align__(16) unsigned short lds[24576];  // 3 bufs x (A 4096 | B 4096)
  const int t = threadIdx.x, w = t >> 6, l = t & 63;
  const int wr = w >> 2, wc = w & 3;     // 2 x 4 waves; wave tile 64 x 32
  const int bx = blockIdx.x, by = blockIdx.y;

  const unsigned short* Ab = A + (size_t)(bx >> 1)*262144 + (bx & 1)*4096 + t*8;
  const unsigned short* Bb = Bt + (size_t)(by >> 1)*262144 + (by & 1)*4096 + t*8;

  f32x4 acc[4][2];
  #pragma unroll
  for (int i = 0; i < 4; i++)
    #pragma unroll
    for (int j = 0; j < 2; j++)
      acc[i][j] = (f32x4){0.f, 0.f, 0.f, 0.f};

  auto stage = [&](int sl){
    const int b = sl % 3;
    const size_t off = (size_t)sl * 8192;
    gll16(Ab + off, &lds[b*8192 + t*8]);
    gll16(Bb + off, &lds[b*8192 + 4096 + t*8]);
  };

  auto phase = [&](int b, bool do_stage, int sl){
    short8 af[4], bfr[2];
    const int aoff = b*8192 + wr*2048 + l*8;
    const int boff = b*8192 + 4096 + wc*1024 + l*8;
    #pragma unroll
    for (int i = 0; i < 4; i++) af[i]  = *(const short8*)&lds[aoff + i*512];
    #pragma unroll
    for (int j = 0; j < 2; j++) bfr[j] = *(const short8*)&lds[boff + j*512];
    if (do_stage) stage(sl);
    __builtin_amdgcn_sched_barrier(0);
    __builtin_amdgcn_s_barrier();
    __builtin_amdgcn_s_setprio(1);
    #pragma unroll
    for (int i = 0; i < 4; i++)
      #pragma unroll
      for (int j = 0; j < 2; j++)
        acc[i][j] = MFMA16(af[i], bfr[j], acc[i][j], 0, 0, 0);
    __builtin_amdgcn_s_setprio(0);
  };

  stage(0); stage(1);
  VMW(2);

  const int NP = 2 * NT;
  int p = 0;
  for (; p <= NP - 3; ++p){
    phase(p % 3, true, p + 2);
    VMW(2);
  }
  phase(p % 3, false, 0); VMW(0); ++p;
  phase(p % 3, false, 0);

  #pragma unroll
  for (int i = 0; i < 4; i++)
    #pragma unroll
    for (int reg = 0; reg < 4; reg++){
      int row = bx*128 + wr*64 + i*16 + (l >> 4)*4 + reg;
      #pragma unroll
      for (int j = 0; j < 2; j++){
        int col = by*128 + wc*32 + j*16 + (l & 15);
        out[(size_t)row * 1024 + col] = acc[i][j][reg] + bias[col];
      }
    }
}

// ---------------- flash attention: 2 waves x 64q (128q blocks), grid 1024 ----
// Same per-wave structure as R13 best (2 q-groups, deferred-PV + T19), but block
// halved to 2 waves so 4 blocks/CU co-reside (4 x 40KB = 160KB LDS exactly):
// same waves/SIMD (2) but from 4 decorrelated blocks -> barrier lockstep spans
// 2 waves instead of 4 and SIMDs carry independent-phase wave pairs.
__global__ __launch_bounds__(128, 2) void k_attn(const unsigned short* __restrict__ Qg,
                                                 const unsigned short* __restrict__ Kg,
                                                 const unsigned short* __restrict__ Vg,
                                                 unsigned short* __restrict__ aout){
  __shared__ __align__(16) unsigned short lds[20480];  // K dbuf:[0,8192) V tri:[8192,20480)

  const int t = threadIdx.x, w = t >> 6, l = t & 63;   // w in {0,1}
  const int hi = l >> 5, q31 = l & 31;
  const int d0 = blockIdx.x;
  const int xcd = d0 & 7, jj = d0 >> 3;        // jj in [0,128)
  const int bh = xcd + 8*(jj >> 4);            // 64 bh values
  const int bx = jj & 15;                      // q-block (128 rows each)

  const unsigned short* Qp = Qg + (size_t)bh*131072 + (size_t)bx*8192;
  const unsigned short* Kp = Kg + (size_t)bh*131072;
  const unsigned short* Vp = Vg + (size_t)bh*131072;

  // ---- stage Q block [128 q][64 d] (16KB) into [0,8192); zero vslot2 ----
  #pragma unroll
  for (int i = 0; i < 8; i++){ int c = i*128 + t; gll16(Qp + c*8, &lds[c*8]); }
  {
    short8 z8 = {0,0,0,0,0,0,0,0};
    #pragma unroll
    for (int j = 0; j < 4; j++)
      *(short8*)&lds[16384 + t*32 + j*8] = z8;   // vslot2: "prev" V at kt=0
  }
  __syncthreads();
  short8 qf0[4], qf1[4];
  #pragma unroll
  for (int ds = 0; ds < 4; ds++){
    qf0[ds] = *(const short8*)&lds[(2*w + 0)*2048 + ds*512 + l*8];
    qf1[ds] = *(const short8*)&lds[(2*w + 1)*2048 + ds*512 + l*8];
  }
  __syncthreads();   // qf reads done before K0/V0 overwrite

  // ---- stage K0 -> kbuf0 [0,4096), V0 -> vslot0 [8192,12288) ----
  #pragma unroll
  for (int i = 0; i < 4; i++){
    int c = i*128 + t;
    gll16(Kp + c*8, &lds[c*8]);
    gll16(Vp + c*8, &lds[8192 + c*8]);
  }
  __syncthreads();   // async gll must drain before kt=0 reads

  f32x16 ZERO;
  #pragma unroll
  for (int i = 0; i < 16; i++) ZERO[i] = 0.f;
  f32x16 o0lo = ZERO, o0hi = ZERO, o1lo = ZERO, o1hi = ZERO;
  float lsum0 = 0.f, lsum1 = 0.f;
  u32x4 pA0[4], pA1[4], pB0[4], pB1[4];
  #pragma unroll
  for (int ks = 0; ks < 4; ks++){
    pA0[ks][0]=0u; pA0[ks][1]=0u; pA0[ks][2]=0u; pA0[ks][3]=0u;
    pA1[ks][0]=0u; pA1[ks][1]=0u; pA1[ks][2]=0u; pA1[ks][3]=0u;
  }
  int s0 = 0, s1 = 1, s2 = 2;

  auto body = [&](int kt, u32x4 (&pO0)[4], u32x4 (&pO1)[4],
                          u32x4 (&pN0)[4], u32x4 (&pN1)[4]){
    const int cbk = (kt & 1) * 4096;
    if (kt < 31){
      const int nbk = cbk ^ 4096;
      const int nv  = 8192 + s1*4096;
      #pragma unroll
      for (int i = 0; i < 4; i++){
        int c = i*128 + t;
        gll16(Kp + (size_t)(kt + 1)*4096 + c*8, &lds[nbk + c*8]);
        gll16(Vp + (size_t)(kt + 1)*4096 + c*8, &lds[nv + c*8]);
      }
    }

    f32x16 sA0, sB0, sA1, sB1;
    __builtin_amdgcn_s_setprio(1);
    {
      short8 kfA = *(const short8*)&lds[cbk + l*8];
      short8 kfB = *(const short8*)&lds[cbk + 2048 + l*8];
      sA0 = MFMA32(kfA, qf0[0], ZERO, 0, 0, 0);
      sB0 = MFMA32(kfB, qf0[0], ZERO, 0, 0, 0);
      sA1 = MFMA32(kfA, qf1[0], ZERO, 0, 0, 0);
      sB1 = MFMA32(kfB, qf1[0], ZERO, 0, 0, 0);
    }
    #pragma unroll
    for (int ds = 1; ds < 4; ds++){
      short8 kfA = *(const short8*)&lds[cbk + ds*512 + l*8];
      short8 kfB = *(const short8*)&lds[cbk + 2048 + ds*512 + l*8];
      sA0 = MFMA32(kfA, qf0[ds], sA0, 0, 0, 0);
      sB0 = MFMA32(kfB, qf0[ds], sB0, 0, 0, 0);
      sA1 = MFMA32(kfA, qf1[ds], sA1, 0, 0, 0);
      sB1 = MFMA32(kfB, qf1[ds], sB1, 0, 0, 0);
    }
    __builtin_amdgcn_s_setprio(0);
    __builtin_amdgcn_sched_barrier(0);

    const int pvb = 8192 + s2*4096;

    #pragma unroll
    for (int i = 0; i < 16; i++){
      sA0[i] = __builtin_amdgcn_exp2f(sA0[i]);
      sB0[i] = __builtin_amdgcn_exp2f(sB0[i]);
      sA1[i] = __builtin_amdgcn_exp2f(sA1[i]);
      sB1[i] = __builtin_amdgcn_exp2f(sB1[i]);
    }
    lsum0 += ((((sA0[0]+sA0[1])+(sA0[2]+sA0[3])) + ((sA0[4]+sA0[5])+(sA0[6]+sA0[7])))
           +  (((sA0[8]+sA0[9])+(sA0[10]+sA0[11])) + ((sA0[12]+sA0[13])+(sA0[14]+sA0[15]))))
           + ((((sB0[0]+sB0[1])+(sB0[2]+sB0[3])) + ((sB0[4]+sB0[5])+(sB0[6]+sB0[7])))
           +  (((sB0[8]+sB0[9])+(sB0[10]+sB0[11])) + ((sB0[12]+sB0[13])+(sB0[14]+sB0[15]))));
    lsum1 += ((((sA1[0]+sA1[1])+(sA1[2]+sA1[3])) + ((sA1[4]+sA1[5])+(sA1[6]+sA1[7])))
           +  (((sA1[8]+sA1[9])+(sA1[10]+sA1[11])) + ((sA1[12]+sA1[13])+(sA1[14]+sA1[15]))))
           + ((((sB1[0]+sB1[1])+(sB1[2]+sB1[3])) + ((sB1[4]+sB1[5])+(sB1[6]+sB1[7])))
           +  (((sB1[8]+sB1[9])+(sB1[10]+sB1[11])) + ((sB1[12]+sB1[13])+(sB1[14]+sB1[15]))));

    {
      unsigned wA[8], wB[8];
      #pragma unroll
      for (int j = 0; j < 8; j++){ wA[j] = cvtpk(sA0[2*j], sA0[2*j+1]); wB[j] = cvtpk(sB0[2*j], sB0[2*j+1]); }
      { unsigned a=wA[0],b=wA[2]; plswap(a,b); pN0[0][0]=a; pN0[0][2]=b; }
      { unsigned a=wA[1],b=wA[3]; plswap(a,b); pN0[0][1]=a; pN0[0][3]=b; }
      { unsigned a=wA[4],b=wA[6]; plswap(a,b); pN0[1][0]=a; pN0[1][2]=b; }
      { unsigned a=wA[5],b=wA[7]; plswap(a,b); pN0[1][1]=a; pN0[1][3]=b; }
      { unsigned a=wB[0],b=wB[2]; plswap(a,b); pN0[2][0]=a; pN0[2][2]=b; }
      { unsigned a=wB[1],b=wB[3]; plswap(a,b); pN0[2][1]=a; pN0[2][3]=b; }
      { unsigned a=wB[4],b=wB[6]; plswap(a,b); pN0[3][0]=a; pN0[3][2]=b; }
      { unsigned a=wB[5],b=wB[7]; plswap(a,b); pN0[3][1]=a; pN0[3][3]=b; }
    }
    {
      unsigned wA[8], wB[8];
      #pragma unroll
      for (int j = 0; j < 8; j++){ wA[j] = cvtpk(sA1[2*j], sA1[2*j+1]); wB[j] = cvtpk(sB1[2*j], sB1[2*j+1]); }
      { unsigned a=wA[0],b=wA[2]; plswap(a,b); pN1[0][0]=a; pN1[0][2]=b; }
      { unsigned a=wA[1],b=wA[3]; plswap(a,b); pN1[0][1]=a; pN1[0][3]=b; }
      { unsigned a=wA[4],b=wA[6]; plswap(a,b); pN1[1][0]=a; pN1[1][2]=b; }
      { unsigned a=wA[5],b=wA[7]; plswap(a,b); pN1[1][1]=a; pN1[1][3]=b; }
      { unsigned a=wB[0],b=wB[2]; plswap(a,b); pN1[2][0]=a; pN1[2][2]=b; }
      { unsigned a=wB[1],b=wB[3]; plswap(a,b); pN1[2][1]=a; pN1[2][3]=b; }
      { unsigned a=wB[4],b=wB[6]; plswap(a,b); pN1[3][0]=a; pN1[3][2]=b; }
      { unsigned a=wB[5],b=wB[7]; plswap(a,b); pN1[3][1]=a; pN1[3][3]=b; }
    }

    #pragma unroll
    for (int ks = 0; ks < 4; ks++){
      short8 p0r, p1r;
      *(u32x4*)&p0r = pO0[ks];
      *(u32x4*)&p1r = pO1[ks];
      short8 vf0 = *(const short8*)&lds[pvb + (ks*2 + 0)*512 + l*8];
      short8 vf1 = *(const short8*)&lds[pvb + (ks*2 + 1)*512 + l*8];
      o0lo = MFMA32(vf0, p0r, o0lo, 0, 0, 0);
      o0hi = MFMA32(vf1, p0r, o0hi, 0, 0, 0);
      o1lo = MFMA32(vf0, p1r, o1lo, 0, 0, 0);
      o1hi = MFMA32(vf1, p1r, o1hi, 0, 0, 0);
    }

    #pragma unroll
    for (int g4 = 0; g4 < 4; g4++){
      __builtin_amdgcn_sched_group_barrier(0x100, 2, 0);   // ds_read (vf pair)
      __builtin_amdgcn_sched_group_barrier(0x002, 40, 0);  // VALU chunk
      __builtin_amdgcn_sched_group_barrier(0x008, 4, 0);   // MFMA quad
    }
    __builtin_amdgcn_sched_group_barrier(0x002, 64, 0);    // remaining VALU

    __syncthreads();
    int tmp = s2; s2 = s0; s0 = s1; s1 = tmp;
  };

  for (int kt2 = 0; kt2 < 32; kt2 += 2){
    body(kt2,     pA0, pA1, pB0, pB1);
    body(kt2 + 1, pB0, pB1, pA0, pA1);
  }

  {
    const int pvb = 8192 + s2*4096;
    __builtin_amdgcn_s_setprio(1);
    #pragma unroll
    for (int ks = 0; ks < 4; ks++){
      short8 p0r, p1r;
      *(u32x4*)&p0r = pA0[ks];
      *(u32x4*)&p1r = pA1[ks];
      short8 vf0 = *(const short8*)&lds[pvb + (ks*2 + 0)*512 + l*8];
      short8 vf1 = *(const short8*)&lds[pvb + (ks*2 + 1)*512 + l*8];
      o0lo = MFMA32(vf0, p0r, o0lo, 0, 0, 0);
      o0hi = MFMA32(vf1, p0r, o0hi, 0, 0, 0);
      o1lo = MFMA32(vf0, p1r, o1lo, 0, 0, 0);
      o1hi = MFMA32(vf1, p1r, o1hi, 0, 0, 0);
    }
    __builtin_amdgcn_s_setprio(0);
  }
  __syncthreads();

  lsum0 += __shfl_xor(lsum0, 32);
  lsum1 += __shfl_xor(lsum1, 32);
  // ---- epilogue: O^T -> LDS (swizzled, 128q x 64d in [0,8192)) -> image stores ----
  {
    float inv0 = 1.0f / lsum0, inv1 = 1.0f / lsum1;
    int qr0 = w*64 + q31, qr1 = w*64 + 32 + q31;   // 0..127 local rows
    #pragma unroll
    for (int j = 0; j < 8; j++){
      int dd0 = 8*(j >> 1) + 2*(j & 1) + 4*hi;
      int dd1 = dd0 + 32;
      *(unsigned*)&lds[qr0*64 + (((dd0 >> 3) ^ (qr0 & 7)) << 3) + (dd0 & 7)] =
          cvtpk(o0lo[2*j] * inv0, o0lo[2*j+1] * inv0);
      *(unsigned*)&lds[qr0*64 + (((dd1 >> 3) ^ (qr0 & 7)) << 3) + (dd1 & 7)] =
          cvtpk(o0hi[2*j] * inv0, o0hi[2*j+1] * inv0);
      *(unsigned*)&lds[qr1*64 + (((dd0 >> 3) ^ (qr1 & 7)) << 3) + (dd0 & 7)] =
          cvtpk(o1lo[2*j] * inv1, o1lo[2*j+1] * inv1);
      *(unsigned*)&lds[qr1*64 + (((dd1 >> 3) ^ (qr1 & 7)) << 3) + (dd1 & 7)] =
          cvtpk(o1hi[2*j] * inv1, o1hi[2*j+1] * inv1);
    }
  }
  __syncthreads();
  {
    int mblk = (bh >> 4)*8 + (bx >> 1);
    int h = bh & 15;
    int bandbase = 8*(bx & 1);
    #pragma unroll
    for (int i = 0; i < 8; i++){
      int idx = i*128 + t;                     // 1024 groups of short8
      int kh = idx >> 9, rem = idx & 511;
      int band_l = rem >> 6, cc = (rem >> 4) & 3, ri = rem & 15;
      int r = band_l*16 + ri, g = kh*4 + cc;
      short8 vv = *(const short8*)&lds[r*64 + ((g ^ (r & 7)) << 3)];
      size_t chunk = (size_t)((mblk*16 + h)*2 + kh);
      *(short8*)&aout[chunk*8192 + (size_t)(bandbase + band_l)*512 + cc*128 + ri*8] = vv;
    }
  }
}

extern "C" void kernel_launch(void* const* d_in, const int* in_sizes, int n_in,
                              void* d_out, int out_size, void* d_ws, size_t ws_size,
                              hipStream_t stream){
  const float* x     = (const float*)d_in[0];
  const float* Wqkv  = (const float*)d_in[1];
  const float* bqkv  = (const float*)d_in[2];
  const float* Wproj = (const float*)d_in[3];
  const float* bproj = (const float*)d_in[4];

  unsigned short* ws   = (unsigned short*)d_ws;
  unsigned short* xb   = ws;                          // 8192*1024 image; reused as attn out
  unsigned short* Wqt  = ws + (size_t)8192 * 1024;    // 3072*1024 image
  unsigned short* Wpt  = Wqt + (size_t)3072 * 1024;   // 1024*1024 image
  unsigned short* qkvb = Wpt + (size_t)1024 * 1024;   // 3 * 64*2048*64 frag images

  k_prep<<<4608, 256, 0, stream>>>(x, xb, Wqkv, Wqt, Wproj, Wpt);
  k_gemm0<<<dim3(64, 12), 512, 0, stream>>>(xb, Wqt, bqkv, qkvb, 16);
  k_attn<<<1024, 128, 0, stream>>>(qkvb, qkvb + (size_t)8388608,
                                   qkvb + (size_t)16777216, xb);
  k_gemmP<<<dim3(64, 8), 512, 0, stream>>>(xb, Wpt, bproj, (float*)d_out, 16);
}

// Round 19
// 152.465 us; speedup vs baseline: 1.0402x; 1.0402x over previous
//
#include <hip/hip_runtime.h>

typedef __attribute__((ext_vector_type(2)))  float  f32x2;
typedef __attribute__((ext_vector_type(4)))  float  f32x4;
typedef __attribute__((ext_vector_type(16))) float  f32x16;
typedef __attribute__((ext_vector_type(8)))  short  short8;
typedef __attribute__((ext_vector_type(4)))  unsigned int u32x4;
typedef __attribute__((ext_vector_type(2)))  unsigned int uint2v;

#define MFMA16 __builtin_amdgcn_mfma_f32_16x16x32_bf16
#define MFMA32 __builtin_amdgcn_mfma_f32_32x32x16_bf16

static __device__ __forceinline__ unsigned short f2bf(float f){
  union { float f; unsigned u; } v; v.f = f;
  unsigned r = v.u + 0x7fffu + ((v.u >> 16) & 1u);
  return (unsigned short)(r >> 16);
}

static __device__ __forceinline__ unsigned cvtpk(float a, float b){
  unsigned r;
  asm("v_cvt_pk_bf16_f32 %0, %1, %2" : "=v"(r) : "v"(a), "v"(b));
  return r;
}

// v_permlane32_swap_b32: a' = {a.lo, b.lo-values}, b' = {a.hi-values, b.hi}
static __device__ __forceinline__ void plswap(unsigned &a, unsigned &b){
  asm("v_permlane32_swap_b32 %0, %1" : "+v"(a), "+v"(b));
}

typedef __attribute__((address_space(1))) void gvoid_t;
typedef __attribute__((address_space(3))) void lvoid_t;

static __device__ __forceinline__ void gll16(const unsigned short* g, unsigned short* l){
  __builtin_amdgcn_global_load_lds((gvoid_t*)g, (lvoid_t*)l, 16, 0, 0);
}

// MFMA-image layout for a [M][1024] bf16 matrix (GEMM staging):
//   chunk = (mblk*16 + kt)*2 + kh ; elem = chunk*8192 + band*512 + c*128 + ri*8 + ke
// Attention fragment images (per bh, per 64-key tile of 4096 elems):
//   Q/K: elem = (row>>5)*2048 + ds*512 + (((d>>3)&1)*32 + (row&31))*8 + (d&7), ds=d>>4
//   V:   elem = (key>>6)*4096 + (((key>>4)&3)*2 + (d>>5))*512 + (((key>>3)&1)*32 + (d&31))*8 + (key&7)

// ---------------- prep: x convert (blocks 0..511) + both W transposes ----------------
__global__ __launch_bounds__(256) void k_prep(const float* __restrict__ x,
                                              unsigned short* __restrict__ xb,
                                              const float* __restrict__ Wq,
                                              unsigned short* __restrict__ Wqt,
                                              const float* __restrict__ Wp,
                                              unsigned short* __restrict__ Wpt){
  __shared__ __align__(16) unsigned char smraw[32768];
  const int bid = blockIdx.x, t = threadIdx.x;
  if (bid < 512){
    unsigned short* sm = (unsigned short*)smraw;     // 256 rows x 64 k
    const int mblk = bid >> 4, kt = bid & 15;
    const int l16 = t & 15, rg = t >> 4;
    #pragma unroll
    for (int p = 0; p < 16; p++){
      int row = p * 16 + rg;
      f32x4 v = *(const f32x4*)&x[(size_t)(mblk*256 + row) * 1024 + kt*64 + l16*4];
      uint2v u; u[0] = cvtpk(v[0], v[1]); u[1] = cvtpk(v[2], v[3]);
      int g = l16 >> 1;
      *(uint2v*)&sm[row*64 + ((g ^ (row & 7)) << 3) + (l16 & 1)*4] = u;
    }
    __syncthreads();
    size_t obase = (size_t)((mblk*16 + kt)*2) * 8192;
    #pragma unroll
    for (int i = 0; i < 8; i++){
      int o = i * 256 + t;
      int kh = o >> 10, rem = o & 1023;
      int band = rem >> 6, cc = (rem >> 4) & 3, ri = rem & 15;
      int r = band*16 + ri, g = kh*4 + cc;
      short8 vv = *(const short8*)&sm[r*64 + ((g ^ (r & 7)) << 3)];
      *(short8*)&xb[obase + (size_t)kh*8192 + rem*8] = vv;
    }
  } else {
    float (*tile)[33] = (float(*)[33])smraw;         // 32 x 33 floats
    int wid = bid - 512;
    const float* W; unsigned short* Wt; int N, n0, k0;
    if (wid < 3072){ W = Wq; Wt = Wqt; N = 3072; n0 = (wid % 96)*32; k0 = (wid / 96)*32; }
    else { wid -= 3072; W = Wp; Wt = Wpt; N = 1024; n0 = (wid & 31)*32; k0 = (wid >> 5)*32; }
    const int tx = t & 31, ty = t >> 5;   // 32 x 8
    #pragma unroll
    for (int r = 0; r < 4; r++)
      tile[ty + 8*r][tx] = W[(size_t)(k0 + ty + 8*r) * N + n0 + tx];
    __syncthreads();
    #pragma unroll
    for (int r = 0; r < 4; r++){
      int nn = ty + 8*r;
      int n = n0 + nn, k = k0 + tx;
      int kt = k >> 6, kh = (k >> 5) & 1, cc = (k >> 3) & 3, ke = k & 7;
      int nblk = n >> 8, band = (n & 255) >> 4, ri = n & 15;
      Wt[(size_t)(((nblk*16 + kt)*2 + kh)) * 8192 + band*512 + cc*128 + ri*8 + ke] =
          f2bf(tile[tx][nn]);
    }
  }
}

// end-of-phase sync with counted vmcnt (N = literal token)
#define VMW(N) { __builtin_amdgcn_sched_barrier(0);                        \
                 asm volatile("s_waitcnt vmcnt(" #N ")" ::: "memory");     \
                 __builtin_amdgcn_s_barrier();                             \
                 __builtin_amdgcn_sched_barrier(0); }

// ---------------- QKV GEMM, 128x256 tile, 8 waves, 3-buffer slice pipeline ----
__global__ __launch_bounds__(512, 4) void k_gemm0(const unsigned short* __restrict__ A,
                                                  const unsigned short* __restrict__ Bt,
                                                  const float* __restrict__ bias,
                                                  unsigned short* __restrict__ qg,
                                                  int NT){
  __shared__ __align__(16) unsigned short lds[36864];
  const int t = threadIdx.x, w = t >> 6, l = t & 63;
  const int wr = w >> 2, wc = w & 3;
  const int bx = blockIdx.x, by = blockIdx.y;
  const int mblk = bx >> 1, mhalf = bx & 1;

  const unsigned short* Ab = A + (size_t)mblk*262144 + mhalf*4096 + t*8;
  const unsigned short* Bb = Bt + (size_t)by*262144 + t*8;

  f32x4 acc[4][4];
  #pragma unroll
  for (int i = 0; i < 4; i++)
    #pragma unroll
    for (int j = 0; j < 4; j++)
      acc[i][j] = (f32x4){0.f, 0.f, 0.f, 0.f};

  auto stage = [&](int sl){
    const int b = sl % 3;
    const size_t off = (size_t)sl * 8192;
    gll16(Ab + off,        &lds[b*12288 + t*8]);
    gll16(Bb + off,        &lds[b*12288 + 4096 + t*8]);
    gll16(Bb + off + 4096, &lds[b*12288 + 8192 + t*8]);
  };

  auto phase = [&](int b, bool do_stage, int sl){
    short8 af[4], bfr[4];
    const int aoff = b*12288 + wr*2048 + l*8;
    const int boff = b*12288 + 4096 + wc*2048 + l*8;
    #pragma unroll
    for (int i = 0; i < 4; i++) af[i]  = *(const short8*)&lds[aoff + i*512];
    #pragma unroll
    for (int j = 0; j < 4; j++) bfr[j] = *(const short8*)&lds[boff + j*512];
    if (do_stage) stage(sl);
    __builtin_amdgcn_sched_barrier(0);
    __builtin_amdgcn_s_barrier();
    __builtin_amdgcn_s_setprio(1);
    #pragma unroll
    for (int i = 0; i < 4; i++)
      #pragma unroll
      for (int j = 0; j < 4; j++)
        acc[i][j] = MFMA16(af[i], bfr[j], acc[i][j], 0, 0, 0);
    __builtin_amdgcn_s_setprio(0);
  };

  stage(0); stage(1);
  VMW(3);

  const int NP = 2 * NT;
  int p = 0;
  for (; p <= NP - 3; ++p){
    phase(p % 3, true, p + 2);
    VMW(3);
  }
  phase(p % 3, false, 0); VMW(0); ++p;
  phase(p % 3, false, 0);

  unsigned short* kg = qg + (size_t)8388608;
  unsigned short* vg = kg + (size_t)8388608;
  const int which = by >> 2;   // 0=q, 1=k, 2=v (block-uniform)
  const int lrow = l & 15;
  #pragma unroll
  for (int j = 0; j < 4; j++){
    int col = by*256 + wc*64 + j*16 + lrow;
    float bi = bias[col];
    int cc = col & 1023;
    int h = cc >> 6;
    int d = j*16 + lrow;
    if (which == 2){
      int db = d >> 5, dd = d & 31;
      #pragma unroll
      for (int i = 0; i < 4; i++){
        int nn = bx*128 + wr*64 + i*16 + (l >> 4)*4;
        int b = nn >> 11, key = nn & 2047;
        size_t idx = (size_t)(key >> 6)*4096 + (size_t)(((key >> 4) & 3)*2 + db)*512
                   + (((key >> 3) & 1)*32 + dd)*8 + (key & 7);
        uint2v u;
        u[0] = cvtpk(acc[i][j][0] + bi, acc[i][j][1] + bi);
        u[1] = cvtpk(acc[i][j][2] + bi, acc[i][j][3] + bi);
        *(uint2v*)&vg[(size_t)(b*16 + h)*131072 + idx] = u;
      }
    } else {
      unsigned short* dst = which ? kg : qg;
      float scale = which ? 1.0f : 0.18033688011f;  // 0.125 * log2(e) for q
      int dsub = (d >> 4)*512 + ((d >> 3) & 1)*256 + (d & 7);
      #pragma unroll
      for (int i = 0; i < 4; i++)
        #pragma unroll
        for (int reg = 0; reg < 4; reg++){
          int nn = bx*128 + wr*64 + i*16 + (l >> 4)*4 + reg;
          int b = nn >> 11, row = nn & 2047;
          dst[(size_t)(b*16 + h)*131072 + (size_t)(row >> 5)*2048 + dsub + (row & 31)*8] =
              f2bf((acc[i][j][reg] + bi) * scale);
        }
    }
  }
}

// ---------------- proj GEMM, 128x128 tile, grid (64,8)=512 blocks, 24KB LDS ----
__global__ __launch_bounds__(512, 4) void k_gemmP(const unsigned short* __restrict__ A,
                                                  const unsigned short* __restrict__ Bt,
                                                  const float* __restrict__ bias,
                                                  float* __restrict__ out,
                                                  int NT){
  __shared__ __align__(16) unsigned short lds[24576];  // 3 bufs x (A 4096 | B 4096)
  const int t = threadIdx.x, w = t >> 6, l = t & 63;
  const int wr = w >> 2, wc = w & 3;     // 2 x 4 waves; wave tile 64 x 32
  const int bx = blockIdx.x, by = blockIdx.y;

  const unsigned short* Ab = A + (size_t)(bx >> 1)*262144 + (bx & 1)*4096 + t*8;
  const unsigned short* Bb = Bt + (size_t)(by >> 1)*262144 + (by & 1)*4096 + t*8;

  f32x4 acc[4][2];
  #pragma unroll
  for (int i = 0; i < 4; i++)
    #pragma unroll
    for (int j = 0; j < 2; j++)
      acc[i][j] = (f32x4){0.f, 0.f, 0.f, 0.f};

  auto stage = [&](int sl){
    const int b = sl % 3;
    const size_t off = (size_t)sl * 8192;
    gll16(Ab + off, &lds[b*8192 + t*8]);
    gll16(Bb + off, &lds[b*8192 + 4096 + t*8]);
  };

  auto phase = [&](int b, bool do_stage, int sl){
    short8 af[4], bfr[2];
    const int aoff = b*8192 + wr*2048 + l*8;
    const int boff = b*8192 + 4096 + wc*1024 + l*8;
    #pragma unroll
    for (int i = 0; i < 4; i++) af[i]  = *(const short8*)&lds[aoff + i*512];
    #pragma unroll
    for (int j = 0; j < 2; j++) bfr[j] = *(const short8*)&lds[boff + j*512];
    if (do_stage) stage(sl);
    __builtin_amdgcn_sched_barrier(0);
    __builtin_amdgcn_s_barrier();
    __builtin_amdgcn_s_setprio(1);
    #pragma unroll
    for (int i = 0; i < 4; i++)
      #pragma unroll
      for (int j = 0; j < 2; j++)
        acc[i][j] = MFMA16(af[i], bfr[j], acc[i][j], 0, 0, 0);
    __builtin_amdgcn_s_setprio(0);
  };

  stage(0); stage(1);
  VMW(2);

  const int NP = 2 * NT;
  int p = 0;
  for (; p <= NP - 3; ++p){
    phase(p % 3, true, p + 2);
    VMW(2);
  }
  phase(p % 3, false, 0); VMW(0); ++p;
  phase(p % 3, false, 0);

  #pragma unroll
  for (int i = 0; i < 4; i++)
    #pragma unroll
    for (int reg = 0; reg < 4; reg++){
      int row = bx*128 + wr*64 + i*16 + (l >> 4)*4 + reg;
      #pragma unroll
      for (int j = 0; j < 2; j++){
        int col = by*128 + wc*32 + j*16 + (l & 15);
        out[(size_t)row * 1024 + col] = acc[i][j][reg] + bias[col];
      }
    }
}

// ---------------- flash attention: 4 waves x 64q, deferred-PV + T19 (R13 exact) ----
__global__ __launch_bounds__(256, 2) void k_attn(const unsigned short* __restrict__ Qg,
                                                 const unsigned short* __restrict__ Kg,
                                                 const unsigned short* __restrict__ Vg,
                                                 unsigned short* __restrict__ aout){
  __shared__ __align__(16) unsigned short lds[20480];  // K:[0,8192) V slots:[8192,20480)

  const int t = threadIdx.x, w = t >> 6, l = t & 63;
  const int hi = l >> 5, q31 = l & 31;
  const int d0 = blockIdx.x;
  const int xcd = d0 & 7, jj = d0 >> 3;        // jj in [0,64)
  const int bh = xcd + 8*(jj >> 3);            // 64 bh values
  const int bx = jj & 7;                       // q-block (256 rows each)

  const unsigned short* Qp = Qg + (size_t)bh*131072 + (size_t)bx*16384;
  const unsigned short* Kp = Kg + (size_t)bh*131072;
  const unsigned short* Vp = Vg + (size_t)bh*131072;

  #pragma unroll
  for (int i = 0; i < 8; i++){ int c = i*256 + t; gll16(Qp + c*8, &lds[c*8]); }
  {
    short8 z8 = {0,0,0,0,0,0,0,0};
    *(short8*)&lds[16384 + t*16]     = z8;   // vslot2: "prev" V at kt=0 (avoid NaN x 0)
    *(short8*)&lds[16384 + t*16 + 8] = z8;
  }
  __syncthreads();
  short8 qf0[4], qf1[4];
  #pragma unroll
  for (int ds = 0; ds < 4; ds++){
    qf0[ds] = *(const short8*)&lds[(2*w + 0)*2048 + ds*512 + l*8];
    qf1[ds] = *(const short8*)&lds[(2*w + 1)*2048 + ds*512 + l*8];
  }
  __syncthreads();

  #pragma unroll
  for (int i = 0; i < 2; i++){
    int c = i*256 + t;
    gll16(Kp + c*8, &lds[c*8]);
    gll16(Vp + c*8, &lds[8192 + c*8]);
  }
  __syncthreads();

  f32x16 ZERO;
  #pragma unroll
  for (int i = 0; i < 16; i++) ZERO[i] = 0.f;
  f32x16 o0lo = ZERO, o0hi = ZERO, o1lo = ZERO, o1hi = ZERO;
  float lsum0 = 0.f, lsum1 = 0.f;
  u32x4 pA0[4], pA1[4], pB0[4], pB1[4];
  #pragma unroll
  for (int ks = 0; ks < 4; ks++){
    pA0[ks][0]=0u; pA0[ks][1]=0u; pA0[ks][2]=0u; pA0[ks][3]=0u;
    pA1[ks][0]=0u; pA1[ks][1]=0u; pA1[ks][2]=0u; pA1[ks][3]=0u;
  }
  int s0 = 0, s1 = 1, s2 = 2;

  auto body = [&](int kt, u32x4 (&pO0)[4], u32x4 (&pO1)[4],
                          u32x4 (&pN0)[4], u32x4 (&pN1)[4]){
    const int cbk = (kt & 1) * 4096;
    if (kt < 31){
      const int nbk = cbk ^ 4096;
      const int nv  = 8192 + s1*4096;
      #pragma unroll
      for (int i = 0; i < 2; i++){
        int c = i*256 + t;
        gll16(Kp + (size_t)(kt + 1)*4096 + c*8, &lds[nbk + c*8]);
        gll16(Vp + (size_t)(kt + 1)*4096 + c*8, &lds[nv + c*8]);
      }
    }

    f32x16 sA0, sB0, sA1, sB1;
    __builtin_amdgcn_s_setprio(1);
    {
      short8 kfA = *(const short8*)&lds[cbk + l*8];
      short8 kfB = *(const short8*)&lds[cbk + 2048 + l*8];
      sA0 = MFMA32(kfA, qf0[0], ZERO, 0, 0, 0);
      sB0 = MFMA32(kfB, qf0[0], ZERO, 0, 0, 0);
      sA1 = MFMA32(kfA, qf1[0], ZERO, 0, 0, 0);
      sB1 = MFMA32(kfB, qf1[0], ZERO, 0, 0, 0);
    }
    #pragma unroll
    for (int ds = 1; ds < 4; ds++){
      short8 kfA = *(const short8*)&lds[cbk + ds*512 + l*8];
      short8 kfB = *(const short8*)&lds[cbk + 2048 + ds*512 + l*8];
      sA0 = MFMA32(kfA, qf0[ds], sA0, 0, 0, 0);
      sB0 = MFMA32(kfB, qf0[ds], sB0, 0, 0, 0);
      sA1 = MFMA32(kfA, qf1[ds], sA1, 0, 0, 0);
      sB1 = MFMA32(kfB, qf1[ds], sB1, 0, 0, 0);
    }
    __builtin_amdgcn_s_setprio(0);
    __builtin_amdgcn_sched_barrier(0);

    const int pvb = 8192 + s2*4096;

    #pragma unroll
    for (int i = 0; i < 16; i++){
      sA0[i] = __builtin_amdgcn_exp2f(sA0[i]);
      sB0[i] = __builtin_amdgcn_exp2f(sB0[i]);
      sA1[i] = __builtin_amdgcn_exp2f(sA1[i]);
      sB1[i] = __builtin_amdgcn_exp2f(sB1[i]);
    }
    lsum0 += ((((sA0[0]+sA0[1])+(sA0[2]+sA0[3])) + ((sA0[4]+sA0[5])+(sA0[6]+sA0[7])))
           +  (((sA0[8]+sA0[9])+(sA0[10]+sA0[11])) + ((sA0[12]+sA0[13])+(sA0[14]+sA0[15]))))
           + ((((sB0[0]+sB0[1])+(sB0[2]+sB0[3])) + ((sB0[4]+sB0[5])+(sB0[6]+sB0[7])))
           +  (((sB0[8]+sB0[9])+(sB0[10]+sB0[11])) + ((sB0[12]+sB0[13])+(sB0[14]+sB0[15]))));
    lsum1 += ((((sA1[0]+sA1[1])+(sA1[2]+sA1[3])) + ((sA1[4]+sA1[5])+(sA1[6]+sA1[7])))
           +  (((sA1[8]+sA1[9])+(sA1[10]+sA1[11])) + ((sA1[12]+sA1[13])+(sA1[14]+sA1[15]))))
           + ((((sB1[0]+sB1[1])+(sB1[2]+sB1[3])) + ((sB1[4]+sB1[5])+(sB1[6]+sB1[7])))
           +  (((sB1[8]+sB1[9])+(sB1[10]+sB1[11])) + ((sB1[12]+sB1[13])+(sB1[14]+sB1[15]))));

    {
      unsigned wA[8], wB[8];
      #pragma unroll
      for (int j = 0; j < 8; j++){ wA[j] = cvtpk(sA0[2*j], sA0[2*j+1]); wB[j] = cvtpk(sB0[2*j], sB0[2*j+1]); }
      { unsigned a=wA[0],b=wA[2]; plswap(a,b); pN0[0][0]=a; pN0[0][2]=b; }
      { unsigned a=wA[1],b=wA[3]; plswap(a,b); pN0[0][1]=a; pN0[0][3]=b; }
      { unsigned a=wA[4],b=wA[6]; plswap(a,b); pN0[1][0]=a; pN0[1][2]=b; }
      { unsigned a=wA[5],b=wA[7]; plswap(a,b); pN0[1][1]=a; pN0[1][3]=b; }
      { unsigned a=wB[0],b=wB[2]; plswap(a,b); pN0[2][0]=a; pN0[2][2]=b; }
      { unsigned a=wB[1],b=wB[3]; plswap(a,b); pN0[2][1]=a; pN0[2][3]=b; }
      { unsigned a=wB[4],b=wB[6]; plswap(a,b); pN0[3][0]=a; pN0[3][2]=b; }
      { unsigned a=wB[5],b=wB[7]; plswap(a,b); pN0[3][1]=a; pN0[3][3]=b; }
    }
    {
      unsigned wA[8], wB[8];
      #pragma unroll
      for (int j = 0; j < 8; j++){ wA[j] = cvtpk(sA1[2*j], sA1[2*j+1]); wB[j] = cvtpk(sB1[2*j], sB1[2*j+1]); }
      { unsigned a=wA[0],b=wA[2]; plswap(a,b); pN1[0][0]=a; pN1[0][2]=b; }
      { unsigned a=wA[1],b=wA[3]; plswap(a,b); pN1[0][1]=a; pN1[0][3]=b; }
      { unsigned a=wA[4],b=wA[6]; plswap(a,b); pN1[1][0]=a; pN1[1][2]=b; }
      { unsigned a=wA[5],b=wA[7]; plswap(a,b); pN1[1][1]=a; pN1[1][3]=b; }
      { unsigned a=wB[0],b=wB[2]; plswap(a,b); pN1[2][0]=a; pN1[2][2]=b; }
      { unsigned a=wB[1],b=wB[3]; plswap(a,b); pN1[2][1]=a; pN1[2][3]=b; }
      { unsigned a=wB[4],b=wB[6]; plswap(a,b); pN1[3][0]=a; pN1[3][2]=b; }
      { unsigned a=wB[5],b=wB[7]; plswap(a,b); pN1[3][1]=a; pN1[3][3]=b; }
    }

    #pragma unroll
    for (int ks = 0; ks < 4; ks++){
      short8 p0r, p1r;
      *(u32x4*)&p0r = pO0[ks];
      *(u32x4*)&p1r = pO1[ks];
      short8 vf0 = *(const short8*)&lds[pvb + (ks*2 + 0)*512 + l*8];
      short8 vf1 = *(const short8*)&lds[pvb + (ks*2 + 1)*512 + l*8];
      o0lo = MFMA32(vf0, p0r, o0lo, 0, 0, 0);
      o0hi = MFMA32(vf1, p0r, o0hi, 0, 0, 0);
      o1lo = MFMA32(vf0, p1r, o1lo, 0, 0, 0);
      o1hi = MFMA32(vf1, p1r, o1hi, 0, 0, 0);
    }

    #pragma unroll
    for (int g4 = 0; g4 < 4; g4++){
      __builtin_amdgcn_sched_group_barrier(0x100, 2, 0);   // ds_read (vf pair)
      __builtin_amdgcn_sched_group_barrier(0x002, 40, 0);  // VALU chunk
      __builtin_amdgcn_sched_group_barrier(0x008, 4, 0);   // MFMA quad
    }
    __builtin_amdgcn_sched_group_barrier(0x002, 64, 0);    // remaining VALU

    __syncthreads();
    int tmp = s2; s2 = s0; s0 = s1; s1 = tmp;
  };

  for (int kt2 = 0; kt2 < 32; kt2 += 2){
    body(kt2,     pA0, pA1, pB0, pB1);
    body(kt2 + 1, pB0, pB1, pA0, pA1);
  }

  {
    const int pvb = 8192 + s2*4096;
    __builtin_amdgcn_s_setprio(1);
    #pragma unroll
    for (int ks = 0; ks < 4; ks++){
      short8 p0r, p1r;
      *(u32x4*)&p0r = pA0[ks];
      *(u32x4*)&p1r = pA1[ks];
      short8 vf0 = *(const short8*)&lds[pvb + (ks*2 + 0)*512 + l*8];
      short8 vf1 = *(const short8*)&lds[pvb + (ks*2 + 1)*512 + l*8];
      o0lo = MFMA32(vf0, p0r, o0lo, 0, 0, 0);
      o0hi = MFMA32(vf1, p0r, o0hi, 0, 0, 0);
      o1lo = MFMA32(vf0, p1r, o1lo, 0, 0, 0);
      o1hi = MFMA32(vf1, p1r, o1hi, 0, 0, 0);
    }
    __builtin_amdgcn_s_setprio(0);
  }
  __syncthreads();

  lsum0 += __shfl_xor(lsum0, 32);
  lsum1 += __shfl_xor(lsum1, 32);
  {
    float inv0 = 1.0f / lsum0, inv1 = 1.0f / lsum1;
    int qr0 = w*64 + q31, qr1 = w*64 + 32 + q31;
    #pragma unroll
    for (int j = 0; j < 8; j++){
      int dd0 = 8*(j >> 1) + 2*(j & 1) + 4*hi;
      int dd1 = dd0 + 32;
      *(unsigned*)&lds[qr0*64 + (((dd0 >> 3) ^ (qr0 & 7)) << 3) + (dd0 & 7)] =
          cvtpk(o0lo[2*j] * inv0, o0lo[2*j+1] * inv0);
      *(unsigned*)&lds[qr0*64 + (((dd1 >> 3) ^ (qr0 & 7)) << 3) + (dd1 & 7)] =
          cvtpk(o0hi[2*j] * inv0, o0hi[2*j+1] * inv0);
      *(unsigned*)&lds[qr1*64 + (((dd0 >> 3) ^ (qr1 & 7)) << 3) + (dd0 & 7)] =
          cvtpk(o1lo[2*j] * inv1, o1lo[2*j+1] * inv1);
      *(unsigned*)&lds[qr1*64 + (((dd1 >> 3) ^ (qr1 & 7)) << 3) + (dd1 & 7)] =
          cvtpk(o1hi[2*j] * inv1, o1hi[2*j+1] * inv1);
    }
  }
  __syncthreads();
  {
    int mblk = (bh >> 4)*8 + bx;
    int h = bh & 15;
    #pragma unroll
    for (int i = 0; i < 8; i++){
      int idx = i*256 + t;
      int kh = idx >> 10, rem = idx & 1023;
      int band = rem >> 6, cc = (rem >> 4) & 3, ri = rem & 15;
      int r = band*16 + ri, g = kh*4 + cc;
      short8 vv = *(const short8*)&lds[r*64 + ((g ^ (r & 7)) << 3)];
      size_t chunk = (size_t)((mblk*16 + h)*2 + kh);
      *(short8*)&aout[chunk*8192 + (size_t)band*512 + cc*128 + ri*8] = vv;
    }
  }
}

extern "C" void kernel_launch(void* const* d_in, const int* in_sizes, int n_in,
                              void* d_out, int out_size, void* d_ws, size_t ws_size,
                              hipStream_t stream){
  const float* x     = (const float*)d_in[0];
  const float* Wqkv  = (const float*)d_in[1];
  const float* bqkv  = (const float*)d_in[2];
  const float* Wproj = (const float*)d_in[3];
  const float* bproj = (const float*)d_in[4];

  unsigned short* ws   = (unsigned short*)d_ws;
  unsigned short* xb   = ws;                          // 8192*1024 image; reused as attn out
  unsigned short* Wqt  = ws + (size_t)8192 * 1024;    // 3072*1024 image
  unsigned short* Wpt  = Wqt + (size_t)3072 * 1024;   // 1024*1024 image
  unsigned short* qkvb = Wpt + (size_t)1024 * 1024;   // 3 * 64*2048*64 frag images

  k_prep<<<4608, 256, 0, stream>>>(x, xb, Wqkv, Wqt, Wproj, Wpt);
  k_gemm0<<<dim3(64, 12), 512, 0, stream>>>(xb, Wqt, bqkv, qkvb, 16);
  k_attn<<<512, 256, 0, stream>>>(qkvb, qkvb + (size_t)8388608,
                                  qkvb + (size_t)16777216, xb);
  k_gemmP<<<dim3(64, 8), 512, 0, stream>>>(xb, Wpt, bproj, (float*)d_out, 16);
}